// Round 8
// baseline (406.152 us; speedup 1.0000x reference)
//
#include <hip/hip_runtime.h>
#include <cstdint>

#define F0 100
#define FH 128
#define FO 64
#define BN_EPS 1e-5f

typedef unsigned short ushort_t;
typedef unsigned int uint_t;

static inline int ceil_div(long long a, long long b) { return (int)((a + b - 1) / b); }

// ---- bf16 helpers (fp32 math everywhere; bf16 is storage only) ----
__device__ __forceinline__ float bf_lo(uint_t w) { return __uint_as_float(w << 16); }
__device__ __forceinline__ float bf_hi(uint_t w) { return __uint_as_float(w & 0xffff0000u); }
__device__ __forceinline__ uint_t f2bf(float f) {  // RNE
  uint_t u = __float_as_uint(f);
  return (u + 0x7fffu + ((u >> 16) & 1u)) >> 16;
}
__device__ __forceinline__ uint_t pack2(float a, float b) {
  return f2bf(a) | (f2bf(b) << 16);
}

// ---------------- GEMM body: out[n x F] = A[n x K] @ W[K x F] (+bias / BN+relu on A) ----

template <int K, int F, int TM, bool BN_A, bool A_BF16, bool OUT_BF16>
__device__ __forceinline__ void gemm2_body(int bid, const void* __restrict__ A_,
                                           const float* __restrict__ W,
                                           const float* __restrict__ bias,
                                           const float* __restrict__ scA,
                                           const float* __restrict__ shA,
                                           void* __restrict__ out_, int n) {
  constexpr int NCG = F / 4;
  constexpr int NRG = 256 / NCG;
  constexpr int BR = NRG * TM;
  constexpr int BK = 32;
  constexpr int F4 = F / 4;

  __shared__ float sW[BK][F];
  __shared__ float sA[BR][BK];

  const int tid = threadIdx.x;
  const int cg = tid % NCG;
  const int rg = tid / NCG;
  const int row0 = bid * BR;

  float4 acc[TM];
#pragma unroll
  for (int t = 0; t < TM; ++t) acc[t] = make_float4(0.f, 0.f, 0.f, 0.f);

  const float4* W4 = (const float4*)W;
  const float4 z4 = make_float4(0.f, 0.f, 0.f, 0.f);

  for (int k0 = 0; k0 < K; k0 += BK) {
    for (int i = tid; i < BK * F4; i += 256) {
      int kk = i / F4, f4 = i % F4;
      int gk = k0 + kk;
      ((float4*)&sW[kk][0])[f4] = (gk < K) ? W4[(size_t)gk * F4 + f4] : z4;
    }
    for (int i = tid; i < BR * (BK / 4); i += 256) {
      int r = i / (BK / 4), k4 = i % (BK / 4);
      int gr = row0 + r;
      int gk = k0 + k4 * 4;
      float4 av = z4;
      if (gr < n && gk + 3 < K) {
        if (A_BF16) {
          uint2 u = ((const uint2*)A_)[(size_t)gr * (K / 4) + (gk >> 2)];
          av.x = bf_lo(u.x); av.y = bf_hi(u.x);
          av.z = bf_lo(u.y); av.w = bf_hi(u.y);
        } else {
          av = ((const float4*)A_)[(size_t)gr * (K / 4) + (gk >> 2)];
        }
        if (BN_A) {
          float4 sc = ((const float4*)scA)[gk >> 2];
          float4 sh = ((const float4*)shA)[gk >> 2];
          av.x = fmaxf(fmaf(av.x, sc.x, sh.x), 0.f);
          av.y = fmaxf(fmaf(av.y, sc.y, sh.y), 0.f);
          av.z = fmaxf(fmaf(av.z, sc.z, sh.z), 0.f);
          av.w = fmaxf(fmaf(av.w, sc.w, sh.w), 0.f);
        }
      }
      ((float4*)&sA[r][0])[k4] = av;
    }
    __syncthreads();
#pragma unroll 4
    for (int kk = 0; kk < BK; ++kk) {
      float4 w = ((const float4*)&sW[kk][0])[cg];
#pragma unroll
      for (int t = 0; t < TM; ++t) {
        float a = sA[rg * TM + t][kk];
        acc[t].x = fmaf(a, w.x, acc[t].x);
        acc[t].y = fmaf(a, w.y, acc[t].y);
        acc[t].z = fmaf(a, w.z, acc[t].z);
        acc[t].w = fmaf(a, w.w, acc[t].w);
      }
    }
    __syncthreads();
  }

  float4 bb = bias ? ((const float4*)bias)[cg] : z4;
#pragma unroll
  for (int t = 0; t < TM; ++t) {
    int gr = row0 + rg * TM + t;
    if (gr < n) {
      float4 v = acc[t];
      v.x += bb.x; v.y += bb.y; v.z += bb.z; v.w += bb.w;
      if (OUT_BF16) {
        ((uint2*)out_)[(size_t)gr * F4 + cg] = make_uint2(pack2(v.x, v.y), pack2(v.z, v.w));
      } else {
        ((float4*)out_)[(size_t)gr * F4 + cg] = v;
      }
    }
  }
}

template <int K, int F, int TM, bool BN_A, bool A_BF16, bool OUT_BF16>
__global__ __launch_bounds__(256) void gemm2_kernel(const void* __restrict__ A,
                                                    const float* __restrict__ W,
                                                    const float* __restrict__ bias,
                                                    const float* __restrict__ scA,
                                                    const float* __restrict__ shA,
                                                    void* __restrict__ out, int n) {
  gemm2_body<K, F, TM, BN_A, A_BF16, OUT_BF16>(blockIdx.x, A, W, bias, scA, shA, out, n);
}

// ---------------- histogram: degr/degc counts + per-edge rank in dst bucket ----------------

__global__ __launch_bounds__(256) void hist_pos_kernel(const int* __restrict__ row,
                                                       const int* __restrict__ col,
                                                       int* __restrict__ degr,
                                                       int* __restrict__ degc,
                                                       int* __restrict__ posw, int E) {
  int e = blockIdx.x * blockDim.x + threadIdx.x;
  if (e >= E) return;
  atomicAdd(&degr[row[e]], 1);
  posw[e] = atomicAdd(&degc[col[e]], 1);
}

// ---------------- scan stage 1: dinv + block-exclusive-scan of degc (partial) ------------

__global__ __launch_bounds__(256) void scan_fused_kernel(const int* __restrict__ degr,
                                                         const int* __restrict__ degc,
                                                         float* __restrict__ dinv,
                                                         int* __restrict__ startp,
                                                         int* __restrict__ bsums, int n) {
  __shared__ int s[256];
  int i = blockIdx.x * 256 + threadIdx.x;
  int dc = 0;
  if (i < n) {
    int dr = degr[i];
    dc = degc[i];
    dinv[i] = (dr > 0) ? rsqrtf((float)dr) : 0.0f;
  }
  s[threadIdx.x] = dc;
  __syncthreads();
  for (int off = 1; off < 256; off <<= 1) {
    int t = 0;
    if (threadIdx.x >= off) t = s[threadIdx.x - off];
    __syncthreads();
    if (threadIdx.x >= off) s[threadIdx.x] += t;
    __syncthreads();
  }
  if (i < n) startp[i] = s[threadIdx.x] - dc;
  if (threadIdx.x == 255) bsums[blockIdx.x] = s[255];
}

__global__ __launch_bounds__(256) void scan_partials_kernel(int* __restrict__ bsums, int nb) {
  __shared__ int s[256];
  int v = (threadIdx.x < nb) ? bsums[threadIdx.x] : 0;
  s[threadIdx.x] = v;
  __syncthreads();
  for (int off = 1; off < 256; off <<= 1) {
    int t = 0;
    if (threadIdx.x >= off) t = s[threadIdx.x - off];
    __syncthreads();
    if (threadIdx.x >= off) s[threadIdx.x] += t;
    __syncthreads();
  }
  if (threadIdx.x < nb) bsums[threadIdx.x] = s[threadIdx.x] - v;
}

// ---------------- fused: csr scatter (atomic-free) || gemm0 (x@W0 -> bufA bf16) ----------
// startA[i] == startp[i] + bsums[i>>8] (scan_add folded into consumers).

__global__ __launch_bounds__(256) void fused_scatter_gemm_kernel(
    const int* __restrict__ row, const int* __restrict__ col, const float* __restrict__ ew,
    const float* __restrict__ dinv, const int* __restrict__ startp,
    const int* __restrict__ bsums, const int* __restrict__ posw, int2* __restrict__ ep, int E,
    const float* __restrict__ A, const float* __restrict__ W, void* __restrict__ out, int n,
    int GB) {
  int bid = blockIdx.x;
  int r5 = bid % 5;
  int g = bid / 5;
  if (r5 == 0 && g < GB) {
    gemm2_body<F0, FH, 8, false, false, true>(g, A, W, nullptr, nullptr, nullptr, out, n);
    return;
  }
  int h = (r5 == 0) ? (bid - GB) : (bid - (g + 1));
  int e = h * 256 + threadIdx.x;
  if (e >= E) return;
  int r = row[e], c = col[e];
  int pos = startp[c] + bsums[c >> 8] + posw[e];
  float coef = dinv[r] * ew[e] * dinv[c];
  ep[pos] = make_int2(r, __float_as_int(coef));
}

// ---------------- conv gather on bf16 input with LDS-staged edge lists ----------------
// Block handles DPB consecutive dsts; their CSR edges are contiguous -> stage chunks of
// 1024 edges into LDS cooperatively (coalesced), consume per-dst from LDS.

template <int F, bool DO_BN, bool OUT_F32>
__global__ __launch_bounds__(256) void conv_bf16_kernel(const ushort_t* __restrict__ x,
                                                        const int* __restrict__ startp,
                                                        const int* __restrict__ bsums,
                                                        const int* __restrict__ degc,
                                                        const int2* __restrict__ ep,
                                                        const float* __restrict__ bias,
                                                        const float* __restrict__ scale,
                                                        const float* __restrict__ shift,
                                                        void* __restrict__ out, int n, int E) {
  constexpr int G2 = F / 8;     // uint4 (8 bf16) groups per row
  constexpr int TPD = G2 / 2;   // threads per dst (2 chunks of 8 features)
  constexpr int DPB = 256 / TPD;
  constexpr int CHUNK = 1024;
  __shared__ int2 eps[CHUNK];

  const int d0 = blockIdx.x * DPB;
  const int dst = d0 + threadIdx.x / TPD;
  const int q = threadIdx.x % TPD;
  const bool valid = dst < n;

  const int blkStart = startp[d0] + bsums[d0 >> 8];
  const int dEnd0 = (d0 + DPB < n) ? (d0 + DPB) : n;
  const int blkEnd = (dEnd0 < n) ? (startp[dEnd0] + bsums[dEnd0 >> 8]) : E;

  int s0 = 0, myEnd = 0;
  if (valid) {
    s0 = startp[dst] + bsums[dst >> 8];
    myEnd = s0 + degc[dst];
  }

  const uint4* x4 = (const uint4*)x;

  float sc[16], sh[16];
  if (DO_BN) {
#pragma unroll
    for (int ch = 0; ch < 2; ++ch) {
      int g = q + ch * TPD;
#pragma unroll
      for (int j = 0; j < 8; ++j) {
        sc[ch * 8 + j] = scale[g * 8 + j];
        sh[ch * 8 + j] = shift[g * 8 + j];
      }
    }
  }

  float acc[16];
#pragma unroll
  for (int j = 0; j < 16; ++j) acc[j] = 0.f;

  for (int cb = blkStart; cb < blkEnd; cb += CHUNK) {
    int cnt = min(CHUNK, blkEnd - cb);
    if (cb != blkStart) __syncthreads();
    for (int i = threadIdx.x; i < cnt; i += 256) eps[i] = ep[cb + i];
    __syncthreads();
    if (valid) {
      int k0 = max(s0, cb);
      int k1 = min(myEnd, cb + cnt);
      for (int k = k0; k < k1; ++k) {
        int2 e = eps[k - cb];
        float c = __int_as_float(e.y);
        const uint4* xp = x4 + (size_t)e.x * G2 + q;
        uint4 v0 = xp[0];
        uint4 v1 = xp[TPD];
        uint_t vv[8] = {v0.x, v0.y, v0.z, v0.w, v1.x, v1.y, v1.z, v1.w};
#pragma unroll
        for (int hh = 0; hh < 8; ++hh) {
          float f0 = bf_lo(vv[hh]);
          float f1 = bf_hi(vv[hh]);
          if (DO_BN) {
            f0 = fmaxf(fmaf(f0, sc[2 * hh], sh[2 * hh]), 0.f);
            f1 = fmaxf(fmaf(f1, sc[2 * hh + 1], sh[2 * hh + 1]), 0.f);
          }
          acc[2 * hh] = fmaf(c, f0, acc[2 * hh]);
          acc[2 * hh + 1] = fmaf(c, f1, acc[2 * hh + 1]);
        }
      }
    }
  }

  if (!valid) return;

  if (bias) {
#pragma unroll
    for (int ch = 0; ch < 2; ++ch) {
      int g = q + ch * TPD;
#pragma unroll
      for (int j = 0; j < 8; ++j) acc[ch * 8 + j] += bias[g * 8 + j];
    }
  }

  if (OUT_F32) {
    float4* o4 = (float4*)out;
    size_t base = (size_t)dst * (F / 4);
    o4[base + 2 * q] = make_float4(acc[0], acc[1], acc[2], acc[3]);
    o4[base + 2 * q + 1] = make_float4(acc[4], acc[5], acc[6], acc[7]);
    o4[base + 2 * (q + TPD)] = make_float4(acc[8], acc[9], acc[10], acc[11]);
    o4[base + 2 * (q + TPD) + 1] = make_float4(acc[12], acc[13], acc[14], acc[15]);
  } else {
    uint4* o4 = (uint4*)out;
    size_t base = (size_t)dst * G2;
    o4[base + q] = make_uint4(pack2(acc[0], acc[1]), pack2(acc[2], acc[3]),
                              pack2(acc[4], acc[5]), pack2(acc[6], acc[7]));
    o4[base + q + TPD] = make_uint4(pack2(acc[8], acc[9]), pack2(acc[10], acc[11]),
                                    pack2(acc[12], acc[13]), pack2(acc[14], acc[15]));
  }
}

// ---------------- BatchNorm stats (bf16 input) + last-block finalize ----------------

__global__ __launch_bounds__(128) void bn_stats_fin_kernel(const ushort_t* __restrict__ z,
                                                           float* __restrict__ sum,
                                                           float* __restrict__ sumsq,
                                                           const float* __restrict__ g,
                                                           const float* __restrict__ be,
                                                           float* __restrict__ scale,
                                                           float* __restrict__ shift,
                                                           int n, int* __restrict__ ctr) {
  int f = threadIdx.x;
  float s = 0.0f, s2 = 0.0f;
  for (int r = blockIdx.x; r < n; r += gridDim.x) {
    float v = __uint_as_float(((uint_t)z[(size_t)r * FH + f]) << 16);
    s += v;
    s2 += v * v;
  }
  unsafeAtomicAdd(&sum[f], s);
  unsafeAtomicAdd(&sumsq[f], s2);
  __threadfence();
  __syncthreads();
  __shared__ int lastFlag;
  if (f == 0) lastFlag = (atomicAdd(ctr, 1) == (int)gridDim.x - 1) ? 1 : 0;
  __syncthreads();
  if (lastFlag) {
    // coherent re-read via atomic-return (avoids stale cache lines)
    float S = atomicAdd(&sum[f], 0.0f);
    float S2 = atomicAdd(&sumsq[f], 0.0f);
    float invN = 1.0f / (float)n;
    float mean = S * invN;
    float var = fmaxf(S2 * invN - mean * mean, 0.0f);
    float sc = g[f] / sqrtf(var + BN_EPS);
    scale[f] = sc;
    shift[f] = be[f] - mean * sc;
  }
}

// ---------------- launch ----------------

extern "C" void kernel_launch(void* const* d_in, const int* in_sizes, int n_in,
                              void* d_out, int out_size, void* d_ws, size_t ws_size,
                              hipStream_t stream) {
  const float* x   = (const float*)d_in[0];
  const int*   ei  = (const int*)d_in[1];
  const float* ew  = (const float*)d_in[2];
  const float* W0  = (const float*)d_in[3];
  const float* b0  = (const float*)d_in[4];
  const float* g0  = (const float*)d_in[5];
  const float* be0 = (const float*)d_in[6];
  const float* W1  = (const float*)d_in[7];
  const float* b1  = (const float*)d_in[8];
  const float* g1  = (const float*)d_in[9];
  const float* be1 = (const float*)d_in[10];
  const float* W2  = (const float*)d_in[11];
  const float* b2  = (const float*)d_in[12];

  const int n = in_sizes[0] / F0;
  const int E = in_sizes[2];
  const int* row = ei;
  const int* col = ei + E;

  // workspace layout
  ushort_t* bufA  = (ushort_t*)d_ws;                    // n*FH bf16
  ushort_t* bufB  = bufA + (size_t)n * FH;              // n*FH bf16
  int2*   ep      = (int2*)(bufB + (size_t)n * FH);     // E int2
  // ---- contiguous zero region: [degc | degr | sum0 sumsq0 sum1 sumsq1 | ctr(2)] ----
  int*    degc    = (int*)(ep + E);                     // n
  int*    degr    = degc + n;                           // n
  float*  sum0    = (float*)(degr + n);                 // 128
  float*  sumsq0  = sum0 + FH;                          // 128
  float*  sum1    = sumsq0 + FH;                        // 128
  float*  sumsq1  = sum1 + FH;                          // 128
  int*    ctr     = (int*)(sumsq1 + FH);                // 2
  const size_t zero_bytes = (2 * (size_t)n + 4 * FH + 2) * 4;
  // ---- rest ----
  int*    startp  = ctr + 2;                            // n
  float*  dinv    = (float*)(startp + n);               // n
  int*    bsums   = (int*)(dinv + n);                   // 256
  float*  scale0  = (float*)(bsums + 256);              // 128
  float*  shift0  = scale0 + FH;
  float*  scale1  = shift0 + FH;
  float*  shift1  = scale1 + FH;
  // transient: posw aliases bufB (consumed by scatter before bufB first written)
  int*    posw    = (int*)bufB;                         // E ints

  const int nb = ceil_div(n, 256);
  const int GB = ceil_div(n, 64);   // gemm blocks (BR=64)
  const int HB = ceil_div(E, 256);  // edge blocks
  const int CB_H = ceil_div(n, 32); // conv blocks F=128 (DPB=32)
  const int CB_O = ceil_div(n, 64); // conv blocks F=64  (DPB=64)

  // --- CSR build ---
  (void)hipMemsetAsync(degc, 0, zero_bytes, stream);
  hist_pos_kernel<<<HB, 256, 0, stream>>>(row, col, degr, degc, posw, E);
  scan_fused_kernel<<<nb, 256, 0, stream>>>(degr, degc, dinv, startp, bsums, n);
  scan_partials_kernel<<<1, 256, 0, stream>>>(bsums, nb);
  // scatter || gemm0 (x@W0 -> bufA bf16)
  fused_scatter_gemm_kernel<<<GB + HB, 256, 0, stream>>>(row, col, ew, dinv, startp, bsums,
                                                         posw, ep, E, x, W0, bufA, n, GB);

  // --- layer 0 tail: z0 = conv(bufA) + b0 -> bufB (bf16); stats0+fin0 ---
  conv_bf16_kernel<FH, false, false><<<CB_H, 256, 0, stream>>>(
      bufA, startp, bsums, degc, ep, b0, nullptr, nullptr, bufB, n, E);
  bn_stats_fin_kernel<<<256, 128, 0, stream>>>(bufB, sum0, sumsq0, g0, be0, scale0, shift0,
                                               n, ctr + 0);

  // --- layer 1: conv(relu(bn0(z0))) -> bufA; gemm W1+b1 -> bufB (z1); stats1+fin1 ---
  conv_bf16_kernel<FH, true, false><<<CB_H, 256, 0, stream>>>(
      bufB, startp, bsums, degc, ep, nullptr, scale0, shift0, bufA, n, E);
  gemm2_kernel<FH, FH, 8, false, true, true><<<GB, 256, 0, stream>>>(
      bufA, W1, b1, nullptr, nullptr, bufB, n);
  bn_stats_fin_kernel<<<256, 128, 0, stream>>>(bufB, sum1, sumsq1, g1, be1, scale1, shift1,
                                               n, ctr + 1);

  // --- final layer (commuted): t2 = relu(bn1(z1)) @ W2 -> bufA (bf16);
  //     out = conv(t2) + b2 -> d_out (fp32) ---
  gemm2_kernel<FH, FO, 4, true, true, true><<<GB, 256, 0, stream>>>(
      bufB, W2, nullptr, scale1, shift1, bufA, n);
  conv_bf16_kernel<FO, false, true><<<CB_O, 256, 0, stream>>>(
      bufA, startp, bsums, degc, ep, b2, nullptr, nullptr, (float*)d_out, n, E);
}